// Round 3
// baseline (1164.903 us; speedup 1.0000x reference)
//
#include <hip/hip_runtime.h>
#include <hip/hip_bf16.h>
#include <cstdint>
#include <cstddef>

// Problem dims (fixed)
#define SEQ 4096
#define DM  512
#define NH  8
#define DPH 64
#define FF  2048

using short8 = __attribute__((ext_vector_type(8))) short;
using f32x4  = __attribute__((ext_vector_type(4))) float;

__device__ inline float b2f(unsigned short u) {
    union { unsigned int i; float f; } c; c.i = ((unsigned int)u) << 16; return c.f;
}
__device__ inline unsigned short f2b(float f) {
    union { float f; unsigned int u; } c; c.f = f;
    unsigned int u = c.u;
    return (unsigned short)((u + 0x7fffu + ((u >> 16) & 1u)) >> 16);
}

// ---------------------------------------------------------------------------
// bf16 MFMA GEMM: C[m][n] = scale * sum_k A[m][k] * BT[n][k]  (+bias, +res, relu)
// A: [M,K] row-major (bf16, or fp32 converted on load if AF32); BT: [N,K] bf16.
// Each wave computes a 16(m) x 64(n) strip; block = 4 waves stacked on m.
// grid = (N/64, M/64, batch)
// ---------------------------------------------------------------------------
template<int AF32>
__global__ __launch_bounds__(256) void gemm_kernel(
    const void* __restrict__ Av, const unsigned short* __restrict__ BT,
    const float* __restrict__ bias, const unsigned short* __restrict__ res,
    unsigned short* __restrict__ Cb, float* __restrict__ Cf,
    int M, int N, int K, long sA, long sB, long sC, float scale, int relu)
{
    const long z = blockIdx.z;
    BT += z * sB;
    const long co = z * sC;

    const int lane = threadIdx.x & 63;
    const int wid  = threadIdx.x >> 6;
    const int quad = lane >> 4;
    const int col  = lane & 15;
    const int m0 = blockIdx.y * 64 + wid * 16;
    const int n0 = blockIdx.x * 64;

    f32x4 acc[4];
    const f32x4 zero4 = {0.f, 0.f, 0.f, 0.f};
#pragma unroll
    for (int t = 0; t < 4; ++t) acc[t] = zero4;

    const unsigned short* arow16 = nullptr;
    const float*          arow32 = nullptr;
    if (AF32) arow32 = (const float*)Av          + z * sA + (size_t)(m0 + col) * K + quad * 8;
    else      arow16 = (const unsigned short*)Av + z * sA + (size_t)(m0 + col) * K + quad * 8;
    const unsigned short* brow = BT + (size_t)(n0 + col) * K + quad * 8;

    for (int k0 = 0; k0 < K; k0 += 32) {
        short8 a;
        if (AF32) {
            const float4 f0 = *(const float4*)(arow32 + k0);
            const float4 f1 = *(const float4*)(arow32 + k0 + 4);
            a[0] = (short)f2b(f0.x); a[1] = (short)f2b(f0.y);
            a[2] = (short)f2b(f0.z); a[3] = (short)f2b(f0.w);
            a[4] = (short)f2b(f1.x); a[5] = (short)f2b(f1.y);
            a[6] = (short)f2b(f1.z); a[7] = (short)f2b(f1.w);
        } else {
            a = *(const short8*)(arow16 + k0);
        }
#pragma unroll
        for (int t = 0; t < 4; ++t) {
            short8 b = *(const short8*)(brow + (size_t)t * 16 * K + k0);
            acc[t] = __builtin_amdgcn_mfma_f32_16x16x32_bf16(a, b, acc[t], 0, 0, 0);
        }
    }

#pragma unroll
    for (int t = 0; t < 4; ++t) {
        const int n = n0 + t * 16 + col;
        const float bv = bias ? bias[n] : 0.f;
#pragma unroll
        for (int r = 0; r < 4; ++r) {
            const int row = m0 + quad * 4 + r;
            float v = acc[t][r] * scale + bv;
            const size_t idx = (size_t)row * N + n;
            if (res)  v += b2f(res[idx]);
            if (relu) v = fmaxf(v, 0.f);
            if (Cf) Cf[co + idx] = v;
            else    Cb[co + idx] = f2b(v);
        }
    }
}

// ---------------------------------------------------------------------------
// fp32 -> bf16 transpose (weights): dst[c][r] = (bf16)src[r][c]
// grid=(C/32, R/32); block=256
// ---------------------------------------------------------------------------
__global__ __launch_bounds__(256) void transpose_cast_kernel(
    const float* __restrict__ src, unsigned short* __restrict__ dst, int R, int C)
{
    __shared__ float tile[32][33];
    const int c0 = blockIdx.x * 32, r0 = blockIdx.y * 32;
    const int tx = threadIdx.x & 31, ty = threadIdx.x >> 5;  // 32 x 8
#pragma unroll
    for (int i = 0; i < 4; ++i)
        tile[ty + i * 8][tx] = src[(size_t)(r0 + ty + i * 8) * C + c0 + tx];
    __syncthreads();
#pragma unroll
    for (int i = 0; i < 4; ++i)
        dst[(size_t)(c0 + ty + i * 8) * R + r0 + tx] = f2b(tile[tx][ty + i * 8]);
}

// ---------------------------------------------------------------------------
// bf16 transpose (per-head V): dst[c][r] = src[r][c]; grid=(C/32, R/32, batch)
// ---------------------------------------------------------------------------
__global__ __launch_bounds__(256) void transpose_kernel(
    const unsigned short* __restrict__ src, unsigned short* __restrict__ dst,
    int R, int C)
{
    __shared__ unsigned short tile[32][33];
    const long off = (long)blockIdx.z * (long)R * (long)C;
    src += off; dst += off;
    const int c0 = blockIdx.x * 32, r0 = blockIdx.y * 32;
    const int tx = threadIdx.x & 31, ty = threadIdx.x >> 5;
#pragma unroll
    for (int i = 0; i < 4; ++i)
        tile[ty + i * 8][tx] = src[(size_t)(r0 + ty + i * 8) * C + c0 + tx];
    __syncthreads();
#pragma unroll
    for (int i = 0; i < 4; ++i)
        dst[(size_t)(c0 + ty + i * 8) * R + r0 + tx] = tile[tx][ty + i * 8];
}

// ---------------------------------------------------------------------------
// fp32 -> bf16 elementwise cast (x). n4 = elements/4.
// ---------------------------------------------------------------------------
__global__ __launch_bounds__(256) void cast_kernel(
    const float* __restrict__ src, unsigned short* __restrict__ dst, int n4)
{
    const int i = blockIdx.x * 256 + threadIdx.x;
    if (i >= n4) return;
    const float4 v = ((const float4*)src)[i];
    union { unsigned short s[4]; unsigned long long u; } p;
    p.s[0] = f2b(v.x); p.s[1] = f2b(v.y); p.s[2] = f2b(v.z); p.s[3] = f2b(v.w);
    ((unsigned long long*)dst)[i] = p.u;
}

// ---------------------------------------------------------------------------
// Fused attention v2 (re-run; R2 bench was an infra failure, not a verdict):
// scores (recompute) + online softmax + attn write + P@V.
// R1 counters: dur 393us, Occupancy 39%, VALUBusy 23%, MfmaUtil 5%, hbm 18%
//   -> latency-bound at 4 blocks/CU. Fix: 4-way col split, 8 blocks/CU.
//
// Block = 256 thr = 4 waves; 16 q-rows per block; wave w takes cols
// [w*1024, w*1024+1024). grid = 2048 (= 8 blocks/CU exactly).
// h = blockIdx.x & 7 keeps one head per XCD L2.
// Phase 1: online (max,sum), ONE exp per tile-row via
//   s' = (v>m) ? s*e+1 : s+e, e = exp(min(m,v)-max(m,v))   [bit-identical]
// then 16-lane shfl reduce + 4-way LDS combine (fixed order, deterministic).
// Phase 2: recompute scores, p = exp(s-m)*inv, write fp32 att once, LDS
// transpose (stride 36) -> bf16 A-frag, accumulate P@V; ctx combined across
// the 4 waves in 2 LDS rounds.
// LDS 18432 B x 8 blocks/CU = 144 KiB <= 160 KiB.
// ---------------------------------------------------------------------------
__global__ __launch_bounds__(256, 8) void fused_attn_kernel(
    const unsigned short* __restrict__ qb,   // [8][4096][64] bf16 (direct view)
    const unsigned short* __restrict__ kb,   // [8][4096][64] bf16
    const unsigned short* __restrict__ vT,   // [8][64][4096] bf16
    float* __restrict__ att,                 // [8][4096][4096] fp32 (output)
    unsigned short* __restrict__ ctx)        // [8][4096][64] bf16
{
    __shared__ __align__(16) float Pl[4][16 * 36];   // per-wave P transpose buf
    __shared__ float smM[4][16];
    __shared__ float smS[4][16];
    __shared__ __align__(16) float cbuf[2][16 * 68]; // ctx combine buffers

    const int id    = blockIdx.x;
    const int h     = id & 7;
    const int strip = id >> 3;               // 0..255
    const int lane  = threadIdx.x & 63;
    const int w     = threadIdx.x >> 6;      // col-quarter 0..3
    const int quad  = lane >> 4, col = lane & 15;
    const int m0    = strip * 16;

    const unsigned short* Qh = qb + (size_t)h * SEQ * DPH;
    const unsigned short* Kh = kb + (size_t)h * SEQ * DPH;
    const unsigned short* Vh = vT + (size_t)h * SEQ * DPH;
    float* atth = att + (size_t)h * SEQ * SEQ;
    unsigned short* ctxh = ctx + (size_t)h * SEQ * DPH;

    // Q fragments for this block's 16 rows (reused by both phases)
    const unsigned short* qrow = Qh + (size_t)(m0 + col) * DPH + quad * 8;
    const short8 aq0 = *(const short8*)(qrow);
    const short8 aq1 = *(const short8*)(qrow + 32);

    const unsigned short* kbase = Kh + (size_t)(w * 1024 + col) * DPH + quad * 8;
    const float SC = 0.125f;
    const f32x4 zero4 = {0.f, 0.f, 0.f, 0.f};

    float m[4], s[4];
#pragma unroll
    for (int r = 0; r < 4; ++r) { m[r] = -1e30f; s[r] = 0.f; }

    // ---- Phase 1: online max/sum over this wave's 1024 columns -------------
#pragma unroll 2
    for (int nt = 0; nt < 64; ++nt) {
        const unsigned short* kr = kbase + (size_t)nt * 16 * DPH;
        const short8 b0 = *(const short8*)(kr);
        const short8 b1 = *(const short8*)(kr + 32);
        f32x4 acc = zero4;
        acc = __builtin_amdgcn_mfma_f32_16x16x32_bf16(aq0, b0, acc, 0, 0, 0);
        acc = __builtin_amdgcn_mfma_f32_16x16x32_bf16(aq1, b1, acc, 0, 0, 0);
#pragma unroll
        for (int r = 0; r < 4; ++r) {
            const float v  = acc[r] * SC;
            const float nm = fmaxf(m[r], v);
            const float e  = __expf(fminf(m[r], v) - nm);   // the one real exp
            s[r] = (v > m[r]) ? fmaf(s[r], e, 1.f) : (s[r] + e);
            m[r] = nm;
        }
    }
    // reduce across the 16 col-lanes (stays inside each quad's 16-lane group)
#pragma unroll
    for (int off = 1; off < 16; off <<= 1) {
#pragma unroll
        for (int r = 0; r < 4; ++r) {
            const float mo = __shfl_xor(m[r], off);
            const float so = __shfl_xor(s[r], off);
            const float nm = fmaxf(m[r], mo);
            s[r] = s[r] * __expf(m[r] - nm) + so * __expf(mo - nm);
            m[r] = nm;
        }
    }
    if (col == 0) {
#pragma unroll
        for (int r = 0; r < 4; ++r) { smM[w][quad * 4 + r] = m[r]; smS[w][quad * 4 + r] = s[r]; }
    }
    __syncthreads();
    // 4-way combine in fixed order -> identical (m, inv) on every wave
    float inv[4];
#pragma unroll
    for (int r = 0; r < 4; ++r) {
        const int row = quad * 4 + r;
        float M = smM[0][row], S = smS[0][row];
#pragma unroll
        for (int ww = 1; ww < 4; ++ww) {
            const float mo = smM[ww][row];
            const float so = smS[ww][row];
            const float nm = fmaxf(M, mo);
            S = S * __expf(M - nm) + so * __expf(mo - nm);
            M = nm;
        }
        m[r] = M;
        inv[r] = 1.f / S;
    }

    // ---- Phase 2: recompute, normalize, write attn, accumulate P@V ---------
    f32x4 cacc[4];
#pragma unroll
    for (int t = 0; t < 4; ++t) cacc[t] = zero4;

    float* Pw = Pl[w];
    float* abase = atth + (size_t)(m0 + quad * 4) * SEQ + w * 1024 + col;
    for (int pr = 0; pr < 32; ++pr) {
#pragma unroll
        for (int sub = 0; sub < 2; ++sub) {
            const int ntl = pr * 2 + sub;
            const unsigned short* kr = kbase + (size_t)ntl * 16 * DPH;
            const short8 b0 = *(const short8*)(kr);
            const short8 b1 = *(const short8*)(kr + 32);
            f32x4 acc = zero4;
            acc = __builtin_amdgcn_mfma_f32_16x16x32_bf16(aq0, b0, acc, 0, 0, 0);
            acc = __builtin_amdgcn_mfma_f32_16x16x32_bf16(aq1, b1, acc, 0, 0, 0);
            float* arow = abase + ntl * 16;
#pragma unroll
            for (int r = 0; r < 4; ++r) {
                const float p = __expf(fmaf(acc[r], SC, -m[r])) * inv[r];
                arow[(size_t)r * SEQ] = p;                       // fp32 attn out
                Pw[(quad * 4 + r) * 36 + sub * 16 + col] = p;    // LDS transpose
            }
        }
        // A-fragment: lane(col,quad) reads P[col][quad*8 .. +7] (fp32 -> bf16)
        const float4 pa0 = *(const float4*)(Pw + col * 36 + quad * 8);
        const float4 pa1 = *(const float4*)(Pw + col * 36 + quad * 8 + 4);
        union { unsigned short us[8]; short8 v; } ap;
        ap.us[0] = f2b(pa0.x); ap.us[1] = f2b(pa0.y);
        ap.us[2] = f2b(pa0.z); ap.us[3] = f2b(pa0.w);
        ap.us[4] = f2b(pa1.x); ap.us[5] = f2b(pa1.y);
        ap.us[6] = f2b(pa1.z); ap.us[7] = f2b(pa1.w);

        const int kg = w * 1024 + pr * 32;
        const unsigned short* vb0 = Vh + (size_t)col * SEQ + kg + quad * 8;
#pragma unroll
        for (int t = 0; t < 4; ++t) {
            const short8 bv = *(const short8*)(vb0 + (size_t)t * 16 * SEQ);
            cacc[t] = __builtin_amdgcn_mfma_f32_16x16x32_bf16(ap.v, bv, cacc[t], 0, 0, 0);
        }
    }

    // ---- combine ctx across 4 col-quarter waves (2 LDS rounds) -------------
    if (w & 1) {           // waves 1,3 store
        float* cb = cbuf[w >> 1];
#pragma unroll
        for (int t = 0; t < 4; ++t)
#pragma unroll
            for (int r = 0; r < 4; ++r)
                cb[(quad * 4 + r) * 68 + t * 16 + col] = cacc[t][r];
    }
    __syncthreads();
    if (!(w & 1)) {        // waves 0,2 accumulate partner
        const float* cb = cbuf[w >> 1];
#pragma unroll
        for (int t = 0; t < 4; ++t)
#pragma unroll
            for (int r = 0; r < 4; ++r)
                cacc[t][r] += cb[(quad * 4 + r) * 68 + t * 16 + col];
    }
    __syncthreads();
    if (w == 2) {          // wave 2 stores its half-sum
#pragma unroll
        for (int t = 0; t < 4; ++t)
#pragma unroll
            for (int r = 0; r < 4; ++r)
                cbuf[0][(quad * 4 + r) * 68 + t * 16 + col] = cacc[t][r];
    }
    __syncthreads();
    if (w == 0) {          // wave 0 finishes and writes
#pragma unroll
        for (int t = 0; t < 4; ++t) {
#pragma unroll
            for (int r = 0; r < 4; ++r) {
                const float v = cacc[t][r] + cbuf[0][(quad * 4 + r) * 68 + t * 16 + col];
                ctxh[(size_t)(m0 + quad * 4 + r) * DPH + t * 16 + col] = f2b(v);
            }
        }
    }
}

// ---------------------------------------------------------------------------
// LayerNorm over rows of 512 fp32 -> fp32 out. One block (256 thr) per row.
// ---------------------------------------------------------------------------
__global__ __launch_bounds__(256) void ln_kernel(
    const float* __restrict__ pre,
    const float* __restrict__ gamma, const float* __restrict__ beta,
    float* __restrict__ out)
{
    __shared__ float redS[4], redQ[4];
    const float* p = pre + (size_t)blockIdx.x * 512;
    const int t = threadIdx.x;
    const int w = t >> 6, lane = t & 63;

    const float2 xv = *(const float2*)(p + t * 2);
    float s = xv.x + xv.y;
    float q = xv.x * xv.x + xv.y * xv.y;
#pragma unroll
    for (int off = 32; off; off >>= 1) {
        s += __shfl_xor(s, off);
        q += __shfl_xor(q, off);
    }
    if (lane == 0) { redS[w] = s; redQ[w] = q; }
    __syncthreads();
    s = redS[0] + redS[1] + redS[2] + redS[3];
    q = redQ[0] + redQ[1] + redQ[2] + redQ[3];

    const float mu  = s * (1.f / 512.f);
    const float var = q * (1.f / 512.f) - mu * mu;
    const float rs  = rsqrtf(var + 1e-5f);

    const size_t o = (size_t)blockIdx.x * 512 + t * 2;
    out[o]     = (xv.x - mu) * rs * gamma[t * 2]     + beta[t * 2];
    out[o + 1] = (xv.y - mu) * rs * gamma[t * 2 + 1] + beta[t * 2 + 1];
}

// ---------------------------------------------------------------------------
extern "C" void kernel_launch(void* const* d_in, const int* in_sizes, int n_in,
                              void* d_out, int out_size, void* d_ws, size_t ws_size,
                              hipStream_t stream)
{
    (void)in_sizes; (void)n_in; (void)out_size; (void)ws_size;

    const float* x     = (const float*)d_in[0];
    const float* wq    = (const float*)d_in[1];
    const float* bq    = (const float*)d_in[2];
    const float* wk    = (const float*)d_in[3];
    const float* bk    = (const float*)d_in[4];
    const float* wv    = (const float*)d_in[5];
    const float* bv    = (const float*)d_in[6];
    const float* wo    = (const float*)d_in[7];
    const float* bo    = (const float*)d_in[8];
    const float* w1    = (const float*)d_in[9];
    const float* b1    = (const float*)d_in[10];
    const float* w2    = (const float*)d_in[11];
    const float* b2    = (const float*)d_in[12];
    const float* gamma = (const float*)d_in[13];
    const float* beta  = (const float*)d_in[14];

    float* out = (float*)d_out;
    float* att = out + (size_t)SEQ * DM;  // attn region: 8*4096*4096 fp32

    char* wsp = (char*)d_ws;
    auto alloc = [&](size_t bytes) {
        char* p = wsp;
        wsp += (bytes + 255) & ~(size_t)255;
        return p;
    };
    unsigned short* wqT  = (unsigned short*)alloc((size_t)DM * DM * 2);
    unsigned short* wkT  = (unsigned short*)alloc((size_t)DM * DM * 2);
    unsigned short* wvT  = (unsigned short*)alloc((size_t)DM * DM * 2);
    unsigned short* woT  = (unsigned short*)alloc((size_t)DM * DM * 2);
    unsigned short* w1T  = (unsigned short*)alloc((size_t)DM * FF * 2);
    unsigned short* w2T  = (unsigned short*)alloc((size_t)FF * DM * 2);
    unsigned short* xb   = (unsigned short*)alloc((size_t)SEQ * DM * 2);
    unsigned short* qb   = (unsigned short*)alloc((size_t)SEQ * DM * 2);
    unsigned short* kb   = (unsigned short*)alloc((size_t)SEQ * DM * 2);
    unsigned short* vb   = (unsigned short*)alloc((size_t)SEQ * DM * 2);
    unsigned short* vT   = (unsigned short*)alloc((size_t)SEQ * DM * 2);
    unsigned short* ctx  = (unsigned short*)alloc((size_t)SEQ * DM * 2);
    unsigned short* aout = (unsigned short*)alloc((size_t)SEQ * DM * 2);
    unsigned short* ffn1 = (unsigned short*)alloc((size_t)SEQ * FF * 2);
    float*          pre  = (float*)alloc((size_t)SEQ * DM * 4);

    const dim3 blk(256);

    // x -> bf16
    cast_kernel<<<dim3((SEQ * DM / 4 + 255) / 256), blk, 0, stream>>>(x, xb, SEQ * DM / 4);

    // Weight transposes+casts -> [out,in] row-major bf16 (BT form)
    transpose_cast_kernel<<<dim3(16, 16), blk, 0, stream>>>(wq, wqT, DM, DM);
    transpose_cast_kernel<<<dim3(16, 16), blk, 0, stream>>>(wk, wkT, DM, DM);
    transpose_cast_kernel<<<dim3(16, 16), blk, 0, stream>>>(wv, wvT, DM, DM);
    transpose_cast_kernel<<<dim3(16, 16), blk, 0, stream>>>(wo, woT, DM, DM);
    transpose_cast_kernel<<<dim3(64, 16), blk, 0, stream>>>(w1, w1T, DM, FF);
    transpose_cast_kernel<<<dim3(16, 64), blk, 0, stream>>>(w2, w2T, FF, DM);

    // Q/K/V projections: [4096,512] = x @ W + b (bf16 out)
    gemm_kernel<0><<<dim3(8, 64, 1), blk, 0, stream>>>(xb, wqT, bq, nullptr, qb, nullptr,
                                                       SEQ, DM, DM, 0, 0, 0, 1.f, 0);
    gemm_kernel<0><<<dim3(8, 64, 1), blk, 0, stream>>>(xb, wkT, bk, nullptr, kb, nullptr,
                                                       SEQ, DM, DM, 0, 0, 0, 1.f, 0);
    gemm_kernel<0><<<dim3(8, 64, 1), blk, 0, stream>>>(xb, wvT, bv, nullptr, vb, nullptr,
                                                       SEQ, DM, DM, 0, 0, 0, 1.f, 0);

    // Per-head V transpose: [4096,64] -> [64,4096], batch=8
    transpose_kernel<<<dim3(2, 128, 8), blk, 0, stream>>>(vb, vT, SEQ, DPH);

    // Fused: scores + softmax + attn write + P@V  (att written once, fp32)
    fused_attn_kernel<<<dim3(2048), blk, 0, stream>>>(qb, kb, vT, att, ctx);

    // attn_out = ctx @ wo + bo + x
    gemm_kernel<0><<<dim3(8, 64, 1), blk, 0, stream>>>(ctx, woT, bo, xb, aout, nullptr,
                                                       SEQ, DM, DM, 0, 0, 0, 1.f, 0);

    // ffn1 = relu(attn_out @ w1 + b1)
    gemm_kernel<0><<<dim3(32, 64, 1), blk, 0, stream>>>(aout, w1T, b1, nullptr, ffn1, nullptr,
                                                        SEQ, FF, DM, 0, 0, 0, 1.f, 1);

    // pre-LN = ffn1 @ w2 + b2 + attn_out (fp32)
    gemm_kernel<0><<<dim3(8, 64, 1), blk, 0, stream>>>(ffn1, w2T, b2, aout, nullptr, pre,
                                                       SEQ, DM, FF, 0, 0, 0, 1.f, 0);

    // LayerNorm -> out (fp32)
    ln_kernel<<<dim3(SEQ), blk, 0, stream>>>(pre, gamma, beta, out);
}

// Round 4
// 982.488 us; speedup vs baseline: 1.1857x; 1.1857x over previous
//
#include <hip/hip_runtime.h>
#include <hip/hip_bf16.h>
#include <cstdint>
#include <cstddef>

// Problem dims (fixed)
#define SEQ 4096
#define DM  512
#define NH  8
#define DPH 64
#define FF  2048

using short8 = __attribute__((ext_vector_type(8))) short;
using f32x4  = __attribute__((ext_vector_type(4))) float;

__device__ inline float b2f(unsigned short u) {
    union { unsigned int i; float f; } c; c.i = ((unsigned int)u) << 16; return c.f;
}
__device__ inline unsigned short f2b(float f) {
    union { float f; unsigned int u; } c; c.f = f;
    unsigned int u = c.u;
    return (unsigned short)((u + 0x7fffu + ((u >> 16) & 1u)) >> 16);
}

// ---------------------------------------------------------------------------
// Tiled bf16 MFMA GEMM (m97-style): C = A @ BT^T (+bias, +res, relu).
// A: [M,K] bf16 row-major; BT: [N,K] bf16 row-major.
// Tile: 128(m) x BN(n), BK=32. Block = 256 thr = 4 waves in 2x2;
// per-wave 64 x BN/2, acc = 4 x NI frags of 16x16 (NI = BN/32).
// LDS: padded [row][40] bf16 (80B stride -> uniform bank spread for b128
// write AND read; rows stay 16B aligned). Reg-staged (global->reg->ds_write),
// 2 barriers per K-step, next-K loads prefetched into regs under the MFMAs.
// K accumulation order identical to previous kernel -> bit-identical output.
// grid = (N/BN, M/128)
// ---------------------------------------------------------------------------
template<int BN, int NI>
__global__ __launch_bounds__(256) void tgemm_kernel(
    const unsigned short* __restrict__ A, const unsigned short* __restrict__ BT,
    const float* __restrict__ bias, const unsigned short* __restrict__ res,
    unsigned short* __restrict__ Cb, float* __restrict__ Cf,
    int M, int N, int K, int relu)
{
    __shared__ __align__(16) unsigned short As[128 * 40];
    __shared__ __align__(16) unsigned short Bs[BN * 40];

    const int t    = threadIdx.x;
    const int lane = t & 63;
    const int wid  = t >> 6;
    const int wr   = wid >> 1, wc = wid & 1;
    const int quad = lane >> 4, cl = lane & 15;
    const int m0 = blockIdx.y * 128;
    const int n0 = blockIdx.x * BN;

    // staging coords: thread t covers (row = t>>2 [+64], 16B k-slot = t&3)
    const int srow = t >> 2;
    const int skc  = t & 3;

    const unsigned short* Arow0 = A  + (size_t)(m0 + srow) * K + skc * 8;
    const unsigned short* Arow1 = Arow0 + (size_t)64 * K;
    const unsigned short* Brow0 = BT + (size_t)(n0 + srow) * K + skc * 8;
    const unsigned short* Brow1 = Brow0 + (size_t)64 * K;

    f32x4 acc[4][NI];
    const f32x4 zero4 = {0.f, 0.f, 0.f, 0.f};
#pragma unroll
    for (int mi = 0; mi < 4; ++mi)
#pragma unroll
        for (int ni = 0; ni < NI; ++ni) acc[mi][ni] = zero4;

    short8 ar0, ar1, br0, br1;
    ar0 = *(const short8*)(Arow0);
    ar1 = *(const short8*)(Arow1);
    br0 = *(const short8*)(Brow0);
    if constexpr (NI == 4) br1 = *(const short8*)(Brow1);

    for (int k0 = 0; k0 < K; k0 += 32) {
        __syncthreads();   // previous step's LDS reads complete
        *(short8*)(&As[srow * 40 + skc * 8])        = ar0;
        *(short8*)(&As[(srow + 64) * 40 + skc * 8]) = ar1;
        *(short8*)(&Bs[srow * 40 + skc * 8])        = br0;
        if constexpr (NI == 4) *(short8*)(&Bs[(srow + 64) * 40 + skc * 8]) = br1;
        __syncthreads();   // tile visible

        const int kn = k0 + 32;
        if (kn < K) {      // prefetch next K-slice; latency hides under MFMAs
            ar0 = *(const short8*)(Arow0 + kn);
            ar1 = *(const short8*)(Arow1 + kn);
            br0 = *(const short8*)(Brow0 + kn);
            if constexpr (NI == 4) br1 = *(const short8*)(Brow1 + kn);
        }

        short8 af[4], bf[NI];
#pragma unroll
        for (int mi = 0; mi < 4; ++mi)
            af[mi] = *(const short8*)(&As[(wr * 64 + mi * 16 + cl) * 40 + quad * 8]);
#pragma unroll
        for (int ni = 0; ni < NI; ++ni)
            bf[ni] = *(const short8*)(&Bs[(wc * (BN / 2) + ni * 16 + cl) * 40 + quad * 8]);
#pragma unroll
        for (int mi = 0; mi < 4; ++mi)
#pragma unroll
            for (int ni = 0; ni < NI; ++ni)
                acc[mi][ni] = __builtin_amdgcn_mfma_f32_16x16x32_bf16(af[mi], bf[ni], acc[mi][ni], 0, 0, 0);
    }

#pragma unroll
    for (int ni = 0; ni < NI; ++ni) {
        const int n = n0 + wc * (BN / 2) + ni * 16 + cl;
        const float bv = bias ? bias[n] : 0.f;
#pragma unroll
        for (int mi = 0; mi < 4; ++mi) {
#pragma unroll
            for (int r = 0; r < 4; ++r) {
                const int row = m0 + wr * 64 + mi * 16 + quad * 4 + r;
                float v = acc[mi][ni][r] + bv;
                const size_t idx = (size_t)row * N + n;
                if (res)  v += b2f(res[idx]);
                if (relu) v = fmaxf(v, 0.f);
                if (Cf) Cf[idx] = v;
                else    Cb[idx] = f2b(v);
            }
        }
    }
}

// ---------------------------------------------------------------------------
// fp32 -> bf16 transpose (weights): dst[c][r] = (bf16)src[r][c]
// grid=(C/32, R/32); block=256
// ---------------------------------------------------------------------------
__global__ __launch_bounds__(256) void transpose_cast_kernel(
    const float* __restrict__ src, unsigned short* __restrict__ dst, int R, int C)
{
    __shared__ float tile[32][33];
    const int c0 = blockIdx.x * 32, r0 = blockIdx.y * 32;
    const int tx = threadIdx.x & 31, ty = threadIdx.x >> 5;  // 32 x 8
#pragma unroll
    for (int i = 0; i < 4; ++i)
        tile[ty + i * 8][tx] = src[(size_t)(r0 + ty + i * 8) * C + c0 + tx];
    __syncthreads();
#pragma unroll
    for (int i = 0; i < 4; ++i)
        dst[(size_t)(c0 + ty + i * 8) * R + r0 + tx] = f2b(tile[tx][ty + i * 8]);
}

// ---------------------------------------------------------------------------
// bf16 transpose (per-head V): dst[c][r] = src[r][c]; grid=(C/32, R/32, batch)
// ---------------------------------------------------------------------------
__global__ __launch_bounds__(256) void transpose_kernel(
    const unsigned short* __restrict__ src, unsigned short* __restrict__ dst,
    int R, int C)
{
    __shared__ unsigned short tile[32][33];
    const long off = (long)blockIdx.z * (long)R * (long)C;
    src += off; dst += off;
    const int c0 = blockIdx.x * 32, r0 = blockIdx.y * 32;
    const int tx = threadIdx.x & 31, ty = threadIdx.x >> 5;
#pragma unroll
    for (int i = 0; i < 4; ++i)
        tile[ty + i * 8][tx] = src[(size_t)(r0 + ty + i * 8) * C + c0 + tx];
    __syncthreads();
#pragma unroll
    for (int i = 0; i < 4; ++i)
        dst[(size_t)(c0 + ty + i * 8) * R + r0 + tx] = tile[tx][ty + i * 8];
}

// ---------------------------------------------------------------------------
// fp32 -> bf16 elementwise cast (x). n4 = elements/4.
// ---------------------------------------------------------------------------
__global__ __launch_bounds__(256) void cast_kernel(
    const float* __restrict__ src, unsigned short* __restrict__ dst, int n4)
{
    const int i = blockIdx.x * 256 + threadIdx.x;
    if (i >= n4) return;
    const float4 v = ((const float4*)src)[i];
    union { unsigned short s[4]; unsigned long long u; } p;
    p.s[0] = f2b(v.x); p.s[1] = f2b(v.y); p.s[2] = f2b(v.z); p.s[3] = f2b(v.w);
    ((unsigned long long*)dst)[i] = p.u;
}

// ---------------------------------------------------------------------------
// Fused attention v3: scores (recompute) + online softmax + attn write + P@V.
// R3 counters: dur 408us @ 77% occupancy, all pipes <25%, hbm == att write
// drain (1.4 TB/s) -> store-pattern-paced. The old path stored p per-element
// as 4 rows x 64B partial lines per instr. v3: the P tile is already in LDS
// for the MFMA transpose; read it back row-major and store 2 float4/lane per
// pr, each instr covering 8 COMPLETE 128B lines (tile row = 32 fp32 = 128B).
// Same floats to the same addresses -> bit-identical output.
// ---------------------------------------------------------------------------
__global__ __launch_bounds__(256, 8) void fused_attn_kernel(
    const unsigned short* __restrict__ qb,   // [8][4096][64] bf16 (direct view)
    const unsigned short* __restrict__ kb,   // [8][4096][64] bf16
    const unsigned short* __restrict__ vT,   // [8][64][4096] bf16
    float* __restrict__ att,                 // [8][4096][4096] fp32 (output)
    unsigned short* __restrict__ ctx)        // [8][4096][64] bf16
{
    __shared__ __align__(16) float Pl[4][16 * 36];   // per-wave P transpose buf
    __shared__ float smM[4][16];
    __shared__ float smS[4][16];
    __shared__ __align__(16) float cbuf[2][16 * 68]; // ctx combine buffers

    const int id    = blockIdx.x;
    const int h     = id & 7;
    const int strip = id >> 3;               // 0..255
    const int lane  = threadIdx.x & 63;
    const int w     = threadIdx.x >> 6;      // col-quarter 0..3
    const int quad  = lane >> 4, col = lane & 15;
    const int m0    = strip * 16;

    const unsigned short* Qh = qb + (size_t)h * SEQ * DPH;
    const unsigned short* Kh = kb + (size_t)h * SEQ * DPH;
    const unsigned short* Vh = vT + (size_t)h * SEQ * DPH;
    float* atth = att + (size_t)h * SEQ * SEQ;
    unsigned short* ctxh = ctx + (size_t)h * SEQ * DPH;

    // Q fragments for this block's 16 rows (reused by both phases)
    const unsigned short* qrow = Qh + (size_t)(m0 + col) * DPH + quad * 8;
    const short8 aq0 = *(const short8*)(qrow);
    const short8 aq1 = *(const short8*)(qrow + 32);

    const unsigned short* kbase = Kh + (size_t)(w * 1024 + col) * DPH + quad * 8;
    const float SC = 0.125f;
    const f32x4 zero4 = {0.f, 0.f, 0.f, 0.f};

    float m[4], s[4];
#pragma unroll
    for (int r = 0; r < 4; ++r) { m[r] = -1e30f; s[r] = 0.f; }

    // ---- Phase 1: online max/sum over this wave's 1024 columns -------------
#pragma unroll 2
    for (int nt = 0; nt < 64; ++nt) {
        const unsigned short* kr = kbase + (size_t)nt * 16 * DPH;
        const short8 b0 = *(const short8*)(kr);
        const short8 b1 = *(const short8*)(kr + 32);
        f32x4 acc = zero4;
        acc = __builtin_amdgcn_mfma_f32_16x16x32_bf16(aq0, b0, acc, 0, 0, 0);
        acc = __builtin_amdgcn_mfma_f32_16x16x32_bf16(aq1, b1, acc, 0, 0, 0);
#pragma unroll
        for (int r = 0; r < 4; ++r) {
            const float v  = acc[r] * SC;
            const float nm = fmaxf(m[r], v);
            const float e  = __expf(fminf(m[r], v) - nm);   // the one real exp
            s[r] = (v > m[r]) ? fmaf(s[r], e, 1.f) : (s[r] + e);
            m[r] = nm;
        }
    }
    // reduce across the 16 col-lanes (stays inside each quad's 16-lane group)
#pragma unroll
    for (int off = 1; off < 16; off <<= 1) {
#pragma unroll
        for (int r = 0; r < 4; ++r) {
            const float mo = __shfl_xor(m[r], off);
            const float so = __shfl_xor(s[r], off);
            const float nm = fmaxf(m[r], mo);
            s[r] = s[r] * __expf(m[r] - nm) + so * __expf(mo - nm);
            m[r] = nm;
        }
    }
    if (col == 0) {
#pragma unroll
        for (int r = 0; r < 4; ++r) { smM[w][quad * 4 + r] = m[r]; smS[w][quad * 4 + r] = s[r]; }
    }
    __syncthreads();
    // 4-way combine in fixed order -> identical (m, inv) on every wave
    float inv[4];
#pragma unroll
    for (int r = 0; r < 4; ++r) {
        const int row = quad * 4 + r;
        float M = smM[0][row], S = smS[0][row];
#pragma unroll
        for (int ww = 1; ww < 4; ++ww) {
            const float mo = smM[ww][row];
            const float so = smS[ww][row];
            const float nm = fmaxf(M, mo);
            S = S * __expf(M - nm) + so * __expf(mo - nm);
            M = nm;
        }
        m[r] = M;
        inv[r] = 1.f / S;
    }

    // ---- Phase 2: recompute, normalize, write attn, accumulate P@V ---------
    f32x4 cacc[4];
#pragma unroll
    for (int t = 0; t < 4; ++t) cacc[t] = zero4;

    float* Pw = Pl[w];
    float* abase = atth + (size_t)m0 * SEQ + w * 1024;   // row base (no quad)
    const int srow2  = lane >> 3;   // 0..7  (att store: row within tile)
    const int schunk = lane & 7;    // 0..7  (att store: 16B chunk in row)
    for (int pr = 0; pr < 32; ++pr) {
#pragma unroll
        for (int sub = 0; sub < 2; ++sub) {
            const int ntl = pr * 2 + sub;
            const unsigned short* kr = kbase + (size_t)ntl * 16 * DPH;
            const short8 b0 = *(const short8*)(kr);
            const short8 b1 = *(const short8*)(kr + 32);
            f32x4 acc = zero4;
            acc = __builtin_amdgcn_mfma_f32_16x16x32_bf16(aq0, b0, acc, 0, 0, 0);
            acc = __builtin_amdgcn_mfma_f32_16x16x32_bf16(aq1, b1, acc, 0, 0, 0);
#pragma unroll
            for (int r = 0; r < 4; ++r) {
                const float p = __expf(fmaf(acc[r], SC, -m[r])) * inv[r];
                Pw[(quad * 4 + r) * 36 + sub * 16 + col] = p;    // LDS transpose
            }
        }
        // att store from LDS: 2 instrs, each = 8 full 128B lines (8 rows x 32 fp32)
#pragma unroll
        for (int sset = 0; sset < 2; ++sset) {
            const int prow = srow2 + sset * 8;
            const float4 pv = *(const float4*)(Pw + prow * 36 + schunk * 4);
            *(float4*)(abase + (size_t)prow * SEQ + pr * 32 + schunk * 4) = pv;
        }
        // A-fragment: lane(col,quad) reads P[col][quad*8 .. +7] (fp32 -> bf16)
        const float4 pa0 = *(const float4*)(Pw + col * 36 + quad * 8);
        const float4 pa1 = *(const float4*)(Pw + col * 36 + quad * 8 + 4);
        union { unsigned short us[8]; short8 v; } ap;
        ap.us[0] = f2b(pa0.x); ap.us[1] = f2b(pa0.y);
        ap.us[2] = f2b(pa0.z); ap.us[3] = f2b(pa0.w);
        ap.us[4] = f2b(pa1.x); ap.us[5] = f2b(pa1.y);
        ap.us[6] = f2b(pa1.z); ap.us[7] = f2b(pa1.w);

        const int kg = w * 1024 + pr * 32;
        const unsigned short* vb0 = Vh + (size_t)col * SEQ + kg + quad * 8;
#pragma unroll
        for (int t = 0; t < 4; ++t) {
            const short8 bv = *(const short8*)(vb0 + (size_t)t * 16 * SEQ);
            cacc[t] = __builtin_amdgcn_mfma_f32_16x16x32_bf16(ap.v, bv, cacc[t], 0, 0, 0);
        }
    }

    // ---- combine ctx across 4 col-quarter waves (2 LDS rounds) -------------
    if (w & 1) {           // waves 1,3 store
        float* cb = cbuf[w >> 1];
#pragma unroll
        for (int t = 0; t < 4; ++t)
#pragma unroll
            for (int r = 0; r < 4; ++r)
                cb[(quad * 4 + r) * 68 + t * 16 + col] = cacc[t][r];
    }
    __syncthreads();
    if (!(w & 1)) {        // waves 0,2 accumulate partner
        const float* cb = cbuf[w >> 1];
#pragma unroll
        for (int t = 0; t < 4; ++t)
#pragma unroll
            for (int r = 0; r < 4; ++r)
                cacc[t][r] += cb[(quad * 4 + r) * 68 + t * 16 + col];
    }
    __syncthreads();
    if (w == 2) {          // wave 2 stores its half-sum
#pragma unroll
        for (int t = 0; t < 4; ++t)
#pragma unroll
            for (int r = 0; r < 4; ++r)
                cbuf[0][(quad * 4 + r) * 68 + t * 16 + col] = cacc[t][r];
    }
    __syncthreads();
    if (w == 0) {          // wave 0 finishes and writes
#pragma unroll
        for (int t = 0; t < 4; ++t) {
#pragma unroll
            for (int r = 0; r < 4; ++r) {
                const float v = cacc[t][r] + cbuf[0][(quad * 4 + r) * 68 + t * 16 + col];
                ctxh[(size_t)(m0 + quad * 4 + r) * DPH + t * 16 + col] = f2b(v);
            }
        }
    }
}

// ---------------------------------------------------------------------------
// LayerNorm over rows of 512 fp32 -> fp32 out. One block (256 thr) per row.
// ---------------------------------------------------------------------------
__global__ __launch_bounds__(256) void ln_kernel(
    const float* __restrict__ pre,
    const float* __restrict__ gamma, const float* __restrict__ beta,
    float* __restrict__ out)
{
    __shared__ float redS[4], redQ[4];
    const float* p = pre + (size_t)blockIdx.x * 512;
    const int t = threadIdx.x;
    const int w = t >> 6, lane = t & 63;

    const float2 xv = *(const float2*)(p + t * 2);
    float s = xv.x + xv.y;
    float q = xv.x * xv.x + xv.y * xv.y;
#pragma unroll
    for (int off = 32; off; off >>= 1) {
        s += __shfl_xor(s, off);
        q += __shfl_xor(q, off);
    }
    if (lane == 0) { redS[w] = s; redQ[w] = q; }
    __syncthreads();
    s = redS[0] + redS[1] + redS[2] + redS[3];
    q = redQ[0] + redQ[1] + redQ[2] + redQ[3];

    const float mu  = s * (1.f / 512.f);
    const float var = q * (1.f / 512.f) - mu * mu;
    const float rs  = rsqrtf(var + 1e-5f);

    const size_t o = (size_t)blockIdx.x * 512 + t * 2;
    out[o]     = (xv.x - mu) * rs * gamma[t * 2]     + beta[t * 2];
    out[o + 1] = (xv.y - mu) * rs * gamma[t * 2 + 1] + beta[t * 2 + 1];
}

// ---------------------------------------------------------------------------
extern "C" void kernel_launch(void* const* d_in, const int* in_sizes, int n_in,
                              void* d_out, int out_size, void* d_ws, size_t ws_size,
                              hipStream_t stream)
{
    (void)in_sizes; (void)n_in; (void)out_size; (void)ws_size;

    const float* x     = (const float*)d_in[0];
    const float* wq    = (const float*)d_in[1];
    const float* bq    = (const float*)d_in[2];
    const float* wk    = (const float*)d_in[3];
    const float* bk    = (const float*)d_in[4];
    const float* wv    = (const float*)d_in[5];
    const float* bv    = (const float*)d_in[6];
    const float* wo    = (const float*)d_in[7];
    const float* bo    = (const float*)d_in[8];
    const float* w1    = (const float*)d_in[9];
    const float* b1    = (const float*)d_in[10];
    const float* w2    = (const float*)d_in[11];
    const float* b2    = (const float*)d_in[12];
    const float* gamma = (const float*)d_in[13];
    const float* beta  = (const float*)d_in[14];

    float* out = (float*)d_out;
    float* att = out + (size_t)SEQ * DM;  // attn region: 8*4096*4096 fp32

    char* wsp = (char*)d_ws;
    auto alloc = [&](size_t bytes) {
        char* p = wsp;
        wsp += (bytes + 255) & ~(size_t)255;
        return p;
    };
    unsigned short* wqT  = (unsigned short*)alloc((size_t)DM * DM * 2);
    unsigned short* wkT  = (unsigned short*)alloc((size_t)DM * DM * 2);
    unsigned short* wvT  = (unsigned short*)alloc((size_t)DM * DM * 2);
    unsigned short* woT  = (unsigned short*)alloc((size_t)DM * DM * 2);
    unsigned short* w1T  = (unsigned short*)alloc((size_t)DM * FF * 2);
    unsigned short* w2T  = (unsigned short*)alloc((size_t)FF * DM * 2);
    unsigned short* xb   = (unsigned short*)alloc((size_t)SEQ * DM * 2);
    unsigned short* qb   = (unsigned short*)alloc((size_t)SEQ * DM * 2);
    unsigned short* kb   = (unsigned short*)alloc((size_t)SEQ * DM * 2);
    unsigned short* vb   = (unsigned short*)alloc((size_t)SEQ * DM * 2);
    unsigned short* vT   = (unsigned short*)alloc((size_t)SEQ * DM * 2);
    unsigned short* ctx  = (unsigned short*)alloc((size_t)SEQ * DM * 2);
    unsigned short* aout = (unsigned short*)alloc((size_t)SEQ * DM * 2);
    unsigned short* ffn1 = (unsigned short*)alloc((size_t)SEQ * FF * 2);
    float*          pre  = (float*)alloc((size_t)SEQ * DM * 4);

    const dim3 blk(256);

    // x -> bf16
    cast_kernel<<<dim3((SEQ * DM / 4 + 255) / 256), blk, 0, stream>>>(x, xb, SEQ * DM / 4);

    // Weight transposes+casts -> [out,in] row-major bf16 (BT form)
    transpose_cast_kernel<<<dim3(16, 16), blk, 0, stream>>>(wq, wqT, DM, DM);
    transpose_cast_kernel<<<dim3(16, 16), blk, 0, stream>>>(wk, wkT, DM, DM);
    transpose_cast_kernel<<<dim3(16, 16), blk, 0, stream>>>(wv, wvT, DM, DM);
    transpose_cast_kernel<<<dim3(16, 16), blk, 0, stream>>>(wo, woT, DM, DM);
    transpose_cast_kernel<<<dim3(64, 16), blk, 0, stream>>>(w1, w1T, DM, FF);
    transpose_cast_kernel<<<dim3(16, 64), blk, 0, stream>>>(w2, w2T, FF, DM);

    // Q/K/V projections: [4096,512] = x @ W + b (bf16 out), tiled GEMM
    tgemm_kernel<64, 2><<<dim3(8, 32), blk, 0, stream>>>(xb, wqT, bq, nullptr, qb, nullptr,
                                                         SEQ, DM, DM, 0);
    tgemm_kernel<64, 2><<<dim3(8, 32), blk, 0, stream>>>(xb, wkT, bk, nullptr, kb, nullptr,
                                                         SEQ, DM, DM, 0);
    tgemm_kernel<64, 2><<<dim3(8, 32), blk, 0, stream>>>(xb, wvT, bv, nullptr, vb, nullptr,
                                                         SEQ, DM, DM, 0);

    // Per-head V transpose: [4096,64] -> [64,4096], batch=8
    transpose_kernel<<<dim3(2, 128, 8), blk, 0, stream>>>(vb, vT, SEQ, DPH);

    // Fused: scores + softmax + attn write + P@V  (att written once, fp32)
    fused_attn_kernel<<<dim3(2048), blk, 0, stream>>>(qb, kb, vT, att, ctx);

    // attn_out = ctx @ wo + bo + x
    tgemm_kernel<64, 2><<<dim3(8, 32), blk, 0, stream>>>(ctx, woT, bo, xb, aout, nullptr,
                                                         SEQ, DM, DM, 0);

    // ffn1 = relu(attn_out @ w1 + b1)
    tgemm_kernel<128, 4><<<dim3(16, 32), blk, 0, stream>>>(aout, w1T, b1, nullptr, ffn1, nullptr,
                                                           SEQ, FF, DM, 1);

    // pre-LN = ffn1 @ w2 + b2 + attn_out (fp32)
    tgemm_kernel<64, 2><<<dim3(8, 32), blk, 0, stream>>>(ffn1, w2T, b2, aout, nullptr, pre,
                                                         SEQ, DM, FF, 0);

    // LayerNorm -> out (fp32)
    ln_kernel<<<dim3(SEQ), blk, 0, stream>>>(pre, gamma, beta, out);
}